// Round 1
// baseline (600.382 us; speedup 1.0000x reference)
//
#include <hip/hip_runtime.h>

#define FEAT 128
#define RANGE 12800
#define NSLICE 64

// ---------- hist: src & dst partial histograms in one dispatch, ushort-packed ----------
__global__ __launch_bounds__(256) void hist_kernel(const int* __restrict__ src,
                                                   const int* __restrict__ dst,
                                                   unsigned* __restrict__ partialD,
                                                   unsigned* __restrict__ partialS,
                                                   int E, int NP) {
    __shared__ unsigned hpk[RANGE / 2];
    int per = (NP / RANGE) * NSLICE;
    int b = blockIdx.x;
    int halfsel = b / per;           // 0 = dst histogram, 1 = src histogram
    int q = b % per;
    int r = q / NSLICE;
    int s = q % NSLICE;
    const int* arr = halfsel ? src : dst;
    unsigned* out = halfsel ? partialS : partialD;
    int v0 = r * RANGE;
    int tid = threadIdx.x;
    for (int i = tid; i < RANGE / 2; i += 256) hpk[i] = 0;
    __syncthreads();
    int e0 = (int)((long long)E * s / NSLICE);
    int e1 = (int)((long long)E * (s + 1) / NSLICE);
    for (int e = e0 + tid; e < e1; e += 256) {
        unsigned d = (unsigned)(arr[e] - v0);
        if (d < RANGE) atomicAdd(&hpk[d >> 1], (d & 1) ? 65536u : 1u);
    }
    __syncthreads();
    size_t wbase = ((size_t)s * NP + v0) >> 1;
    for (int i = tid; i < RANGE / 2; i += 256) out[wbase + i] = hpk[i];
}

// ---------- scan phase 1: per-node slice-sums + deg_in + norms ----------
__global__ __launch_bounds__(256) void scanp1_kernel(const unsigned short* __restrict__ pD,
                                                     const unsigned short* __restrict__ pS,
                                                     int* __restrict__ blockSums,
                                                     float* __restrict__ ns,
                                                     float* __restrict__ nd,
                                                     int NP, int n) {
    __shared__ int buf[256];
    int tid = threadIdx.x;
    int v = blockIdx.x * 256 + tid;
    int ssum = 0, osum = 0;
    #pragma unroll
    for (int s = 0; s < NSLICE; ++s) {
        ssum += pD[(size_t)s * NP + v];
        osum += pS[(size_t)s * NP + v];
    }
    if (v < n) {
        ns[v] = 1.0f / sqrtf((float)(osum < 1 ? 1 : osum));
        nd[v] = 1.0f / sqrtf((float)(ssum < 1 ? 1 : ssum));
    }
    buf[tid] = ssum;
    __syncthreads();
    #pragma unroll
    for (int off = 1; off < 256; off <<= 1) {
        int t = (tid >= off) ? buf[tid - off] : 0;
        __syncthreads();
        buf[tid] += t;
        __syncthreads();
    }
    if (tid == 255) blockSums[blockIdx.x] = buf[255];
}

// ---------- scan phase 2 ----------
__global__ __launch_bounds__(256) void scanp2_kernel(const int* __restrict__ blockSums,
                                                     int* __restrict__ blockOffs, int nb) {
    __shared__ int buf[256];
    int tid = threadIdx.x;
    int v = (tid < nb) ? blockSums[tid] : 0;
    buf[tid] = v;
    __syncthreads();
    #pragma unroll
    for (int off = 1; off < 256; off <<= 1) {
        int t = (tid >= off) ? buf[tid - off] : 0;
        __syncthreads();
        buf[tid] += t;
        __syncthreads();
    }
    if (tid < nb) blockOffs[tid] = buf[tid] - v;
}

// ---------- scan phase 3: per-(node,slice) cursors + compact offsets ----------
__global__ __launch_bounds__(256) void scanp3_kernel(const unsigned short* __restrict__ pD,
                                                     const int* __restrict__ blockOffs,
                                                     int* __restrict__ cursorV,
                                                     int* __restrict__ offsc,
                                                     int NP, int n) {
    __shared__ int buf[256];
    int tid = threadIdx.x;
    int v = blockIdx.x * 256 + tid;
    int ssum = 0;
    #pragma unroll
    for (int s = 0; s < NSLICE; ++s) ssum += pD[(size_t)s * NP + v];
    buf[tid] = ssum;
    __syncthreads();
    #pragma unroll
    for (int off = 1; off < 256; off <<= 1) {
        int t = (tid >= off) ? buf[tid - off] : 0;
        __syncthreads();
        buf[tid] += t;
        __syncthreads();
    }
    int o = blockOffs[blockIdx.x] + buf[tid] - ssum;
    if (v <= n) offsc[v] = o;          // pad nodes have zero edges -> v==n gets total
    int* cv = cursorV + (size_t)v * NSLICE;
    #pragma unroll
    for (int s = 0; s < NSLICE; ++s) {
        int val = pD[(size_t)s * NP + v];
        cv[s] = o;
        o += val;
    }
}

// ---------- fill: place edges via LDS cursors (XCD-swizzled slices) ----------
__global__ __launch_bounds__(256) void fill_kernel(const int* __restrict__ src,
                                                   const int* __restrict__ dst,
                                                   const int* __restrict__ cursorV,
                                                   int* __restrict__ esrc, int E, int NP) {
    __shared__ int cur[RANGE];
    int b = blockIdx.x;
    int r = b / NSLICE;
    int inner = b % NSLICE;
    int s = ((inner & 7) << 3) | (inner >> 3);
    int v0 = r * RANGE;
    int tid = threadIdx.x;
    for (int i = tid; i < RANGE; i += 256)
        cur[i] = cursorV[(size_t)(v0 + i) * NSLICE + s];
    __syncthreads();
    int e0 = (int)((long long)E * s / NSLICE);
    int e1 = (int)((long long)E * (s + 1) / NSLICE);
    for (int e = e0 + tid; e < e1; e += 256) {
        unsigned dd = (unsigned)(dst[e] - v0);
        if (dd < RANGE) {
            int p = atomicAdd(&cur[dd], 1);
            esrc[p] = src[e];
        }
    }
}

__device__ __forceinline__ void acc4(float4& A, const float4 t, float w) {
    A.x = fmaf(t.x, w, A.x); A.y = fmaf(t.y, w, A.y);
    A.z = fmaf(t.z, w, A.z); A.w = fmaf(t.w, w, A.w);
}

// ---------- aggregation: quarter-wave per edge stream, 16 rows in flight per wave ----------
// SCALE=1: gather in_feat[src]*ns[src] (fuses the old prescale kernel for layer 0)
template<int SCALE>
__global__ __launch_bounds__(256) void agg_kernel(const float* __restrict__ x,
                                                  const int* __restrict__ offs,
                                                  const int* __restrict__ esrc,
                                                  const float* __restrict__ nd,
                                                  const float* __restrict__ nsv,
                                                  float* __restrict__ m, int n) {
    int gid = blockIdx.x * blockDim.x + threadIdx.x;
    int v = gid >> 6;
    if (v >= n) return;
    int lane = threadIdx.x & 63;
    int q = lane >> 4;       // quarter 0..3: independent edge stream, stride 4
    int c = lane & 15;       // 16 lanes cover a 128-float row as 2 float4 each
    int s0 = offs[v], s1 = offs[v + 1];
    float4 A0 = {0,0,0,0}, B0 = {0,0,0,0};
    float4 A1 = {0,0,0,0}, B1 = {0,0,0,0};
    float4 A2 = {0,0,0,0}, B2 = {0,0,0,0};
    float4 A3 = {0,0,0,0}, B3 = {0,0,0,0};
    int j = s0 + q;
    // main: 4 edges per quarter in flight -> 8 float4 loads outstanding per lane
    for (; j + 12 < s1; j += 16) {
        int e0 = esrc[j], e1 = esrc[j + 4], e2 = esrc[j + 8], e3 = esrc[j + 12];
        const float4* p0 = (const float4*)(x + (size_t)e0 * FEAT);
        const float4* p1 = (const float4*)(x + (size_t)e1 * FEAT);
        const float4* p2 = (const float4*)(x + (size_t)e2 * FEAT);
        const float4* p3 = (const float4*)(x + (size_t)e3 * FEAT);
        float4 t0a = p0[c], t0b = p0[c + 16];
        float4 t1a = p1[c], t1b = p1[c + 16];
        float4 t2a = p2[c], t2b = p2[c + 16];
        float4 t3a = p3[c], t3b = p3[c + 16];
        float w0 = SCALE ? nsv[e0] : 1.0f;
        float w1 = SCALE ? nsv[e1] : 1.0f;
        float w2 = SCALE ? nsv[e2] : 1.0f;
        float w3 = SCALE ? nsv[e3] : 1.0f;
        acc4(A0, t0a, w0); acc4(B0, t0b, w0);
        acc4(A1, t1a, w1); acc4(B1, t1b, w1);
        acc4(A2, t2a, w2); acc4(B2, t2b, w2);
        acc4(A3, t3a, w3); acc4(B3, t3b, w3);
    }
    // pair remainder
    if (j + 4 < s1) {
        int e0 = esrc[j], e1 = esrc[j + 4];
        const float4* p0 = (const float4*)(x + (size_t)e0 * FEAT);
        const float4* p1 = (const float4*)(x + (size_t)e1 * FEAT);
        float4 t0a = p0[c], t0b = p0[c + 16];
        float4 t1a = p1[c], t1b = p1[c + 16];
        float w0 = SCALE ? nsv[e0] : 1.0f;
        float w1 = SCALE ? nsv[e1] : 1.0f;
        acc4(A0, t0a, w0); acc4(B0, t0b, w0);
        acc4(A1, t1a, w1); acc4(B1, t1b, w1);
        j += 8;
    }
    // single remainder
    if (j < s1) {
        int e0 = esrc[j];
        const float4* p0 = (const float4*)(x + (size_t)e0 * FEAT);
        float4 t0a = p0[c], t0b = p0[c + 16];
        float w0 = SCALE ? nsv[e0] : 1.0f;
        acc4(A0, t0a, w0); acc4(B0, t0b, w0);
    }
    float r[8];
    r[0] = A0.x + A1.x + A2.x + A3.x;
    r[1] = A0.y + A1.y + A2.y + A3.y;
    r[2] = A0.z + A1.z + A2.z + A3.z;
    r[3] = A0.w + A1.w + A2.w + A3.w;
    r[4] = B0.x + B1.x + B2.x + B3.x;
    r[5] = B0.y + B1.y + B2.y + B3.y;
    r[6] = B0.z + B1.z + B2.z + B3.z;
    r[7] = B0.w + B1.w + B2.w + B3.w;
    #pragma unroll
    for (int i = 0; i < 8; ++i) {
        r[i] += __shfl_xor(r[i], 16);
        r[i] += __shfl_xor(r[i], 32);
    }
    if (lane < 16) {
        float sc = nd[v];
        float4 ra, rb;
        ra.x = r[0] * sc; ra.y = r[1] * sc; ra.z = r[2] * sc; ra.w = r[3] * sc;
        rb.x = r[4] * sc; rb.y = r[5] * sc; rb.z = r[6] * sc; rb.w = r[7] * sc;
        ((float4*)(m + (size_t)v * FEAT))[c] = ra;
        ((float4*)(m + (size_t)v * FEAT))[c + 16] = rb;
    }
}

// ---------- GEMM: 128x128 tile, 256 threads (4 waves), 8x8 blocking ----------
template<int MODE>   // 0: relu*ns (mid layer)   1: last layer (h + threshold)
__global__ __launch_bounds__(256) void gemm_kernel(const float* __restrict__ M,
                                                   const float* __restrict__ W,
                                                   const float* __restrict__ bias,
                                                   const float* __restrict__ nsv,
                                                   float* __restrict__ out,
                                                   float* __restrict__ out2, int n) {
    __shared__ float MsT[32][132];   // [k][row] transposed, stride 132 (16B-aligned, odd/32 banks)
    __shared__ float Ws[32][128];
    __shared__ float ns_s[128];
    int tid = threadIdx.x;
    int tx = tid & 15;     // cols tx*4..+3 and 64+tx*4..+3
    int ty = tid >> 4;     // rows ty*8..+7  (16 groups x 8 = 128 rows)
    int r0 = blockIdx.x * 128;
    if (MODE == 0 && tid < 128) ns_s[tid] = (r0 + tid < n) ? nsv[r0 + tid] : 1.0f;

    float acc[8][8];
    #pragma unroll
    for (int r = 0; r < 8; ++r)
        #pragma unroll
        for (int i = 0; i < 8; ++i) acc[r][i] = 0.f;

    for (int k0 = 0; k0 < FEAT; k0 += 32) {
        if (k0) __syncthreads();
        // stage W chunk: 1024 float4, 4 per thread
        #pragma unroll
        for (int i = 0; i < 4; ++i) {
            int idx = tid + i * 256;
            ((float4*)&Ws[0][0])[idx] = ((const float4*)(W + (size_t)k0 * FEAT))[idx];
        }
        // stage M tile transposed: 1024 float4, 4 per thread
        #pragma unroll
        for (int jj = 0; jj < 4; ++jj) {
            int i = tid + jj * 256;
            int row = i >> 3, c4 = i & 7;
            int gr = r0 + row;
            float4 v = make_float4(0.f, 0.f, 0.f, 0.f);
            if (gr < n) v = *(const float4*)(M + (size_t)gr * FEAT + k0 + c4 * 4);
            MsT[c4 * 4 + 0][row] = v.x;
            MsT[c4 * 4 + 1][row] = v.y;
            MsT[c4 * 4 + 2][row] = v.z;
            MsT[c4 * 4 + 3][row] = v.w;
        }
        __syncthreads();
        #pragma unroll 8
        for (int kk = 0; kk < 32; ++kk) {
            float4 a0 = *(const float4*)&MsT[kk][ty * 8];
            float4 a1 = *(const float4*)&MsT[kk][ty * 8 + 4];
            float4 w0 = *(const float4*)&Ws[kk][tx * 4];
            float4 w1 = *(const float4*)&Ws[kk][64 + tx * 4];
            float a[8] = {a0.x, a0.y, a0.z, a0.w, a1.x, a1.y, a1.z, a1.w};
            float w[8] = {w0.x, w0.y, w0.z, w0.w, w1.x, w1.y, w1.z, w1.w};
            #pragma unroll
            for (int r = 0; r < 8; ++r)
                #pragma unroll
                for (int i = 0; i < 8; ++i)
                    acc[r][i] = fmaf(a[r], w[i], acc[r][i]);
        }
    }

    float4 b0 = *(const float4*)&bias[tx * 4];
    float4 b1 = *(const float4*)&bias[64 + tx * 4];
    #pragma unroll
    for (int r = 0; r < 8; ++r) {
        int row = r0 + ty * 8 + r;
        if (row < n) {
            float4 v0, v1;
            v0.x = acc[r][0] + b0.x; v0.y = acc[r][1] + b0.y;
            v0.z = acc[r][2] + b0.z; v0.w = acc[r][3] + b0.w;
            v1.x = acc[r][4] + b1.x; v1.y = acc[r][5] + b1.y;
            v1.z = acc[r][6] + b1.z; v1.w = acc[r][7] + b1.w;
            v0.x = v0.x > 0.f ? v0.x : 0.f; v0.y = v0.y > 0.f ? v0.y : 0.f;
            v0.z = v0.z > 0.f ? v0.z : 0.f; v0.w = v0.w > 0.f ? v0.w : 0.f;
            v1.x = v1.x > 0.f ? v1.x : 0.f; v1.y = v1.y > 0.f ? v1.y : 0.f;
            v1.z = v1.z > 0.f ? v1.z : 0.f; v1.w = v1.w > 0.f ? v1.w : 0.f;
            if (MODE == 0) {
                float sc_ = ns_s[ty * 8 + r];
                v0.x *= sc_; v0.y *= sc_; v0.z *= sc_; v0.w *= sc_;
                v1.x *= sc_; v1.y *= sc_; v1.z *= sc_; v1.w *= sc_;
            }
            *(float4*)(out + (size_t)row * FEAT + tx * 4) = v0;
            *(float4*)(out + (size_t)row * FEAT + 64 + tx * 4) = v1;
            if (MODE == 1) {
                float4 c0, c1;
                c0.x = v0.x >= 0.5f ? 1.f : 0.f; c0.y = v0.y >= 0.5f ? 1.f : 0.f;
                c0.z = v0.z >= 0.5f ? 1.f : 0.f; c0.w = v0.w >= 0.5f ? 1.f : 0.f;
                c1.x = v1.x >= 0.5f ? 1.f : 0.f; c1.y = v1.y >= 0.5f ? 1.f : 0.f;
                c1.z = v1.z >= 0.5f ? 1.f : 0.f; c1.w = v1.w >= 0.5f ? 1.f : 0.f;
                *(float4*)(out2 + (size_t)row * FEAT + tx * 4) = c0;
                *(float4*)(out2 + (size_t)row * FEAT + 64 + tx * 4) = c1;
            }
        }
    }
}

extern "C" void kernel_launch(void* const* d_in, const int* in_sizes, int n_in,
                              void* d_out, int out_size, void* d_ws, size_t ws_size,
                              hipStream_t stream) {
    const float* in_feat = (const float*)d_in[0];
    const int*   src     = (const int*)d_in[1];
    const int*   dst     = (const int*)d_in[2];
    const float* W[5] = {(const float*)d_in[3], (const float*)d_in[5], (const float*)d_in[7],
                         (const float*)d_in[9], (const float*)d_in[11]};
    const float* B[5] = {(const float*)d_in[4], (const float*)d_in[6], (const float*)d_in[8],
                         (const float*)d_in[10], (const float*)d_in[12]};
    const int E = in_sizes[1];
    const int N = in_sizes[0] / FEAT;
    const int NRANGE = (N + RANGE - 1) / RANGE;       // 4
    const int NP = NRANGE * RANGE;                    // 51200
    const size_t MTOT = (size_t)NP * NSLICE;          // 3,276,800

    char* ws = (char*)d_ws;
    size_t off = 0;
    auto alloc = [&](size_t bytes) { size_t o = off; off += (bytes + 255) & ~size_t(255); return o; };
    unsigned* partialD = (unsigned*)(ws + alloc(MTOT * 2));
    size_t    pS_off   = alloc(MTOT * 2);
    unsigned* partialS = (unsigned*)(ws + pS_off);
    int*      esrc     = (int*)(ws + pS_off);          // aliases partialS (dead after scanp1)
    int*      cursorV  = (int*)(ws + alloc(MTOT * 4));
    float*    ns       = (float*)(ws + alloc((size_t)N * 4));
    float*    nd       = (float*)(ws + alloc((size_t)N * 4));
    int*      offsc    = (int*)(ws + alloc((size_t)(N + 1) * 4));
    int*      blockSums = (int*)(ws + alloc(1024));
    int*      blockOffs = (int*)(ws + alloc(1024));

    float* out_h = (float*)d_out;                     // m scratch; h5 at the end
    float* out_c = out_h + (size_t)N * FEAT;          // scaled-h chain; threshold at end

    const int histBlocks = 2 * NRANGE * NSLICE;       // 512
    const int scanBlocks = NP / 256;                  // 200
    hist_kernel<<<histBlocks, 256, 0, stream>>>(src, dst, partialD, partialS, E, NP);
    scanp1_kernel<<<scanBlocks, 256, 0, stream>>>((const unsigned short*)partialD,
                                                  (const unsigned short*)partialS,
                                                  blockSums, ns, nd, NP, N);
    scanp2_kernel<<<1, 256, 0, stream>>>(blockSums, blockOffs, scanBlocks);
    scanp3_kernel<<<scanBlocks, 256, 0, stream>>>((const unsigned short*)partialD,
                                                  blockOffs, cursorV, offsc, NP, N);
    fill_kernel<<<NRANGE * NSLICE, 256, 0, stream>>>(src, dst, cursorV, esrc, E, NP);

    const int agg_blocks = (int)(((size_t)N * 64 + 255) / 256);
    const int gemm_blocks = (N + 127) / 128;

    for (int l = 0; l < 5; ++l) {
        if (l == 0)
            agg_kernel<1><<<agg_blocks, 256, 0, stream>>>(in_feat, offsc, esrc, nd, ns, out_h, N);
        else
            agg_kernel<0><<<agg_blocks, 256, 0, stream>>>(out_c, offsc, esrc, nd, nullptr, out_h, N);
        if (l < 4)
            gemm_kernel<0><<<gemm_blocks, 256, 0, stream>>>(out_h, W[l], B[l], ns, out_c, nullptr, N);
        else
            gemm_kernel<1><<<gemm_blocks, 256, 0, stream>>>(out_h, W[l], B[l], ns, out_h, out_c, N);
    }
}

// Round 2
// 526.723 us; speedup vs baseline: 1.1398x; 1.1398x over previous
//
#include <hip/hip_runtime.h>

#define FEAT 128
#define RANGE 12800
#define NSLICE 64

typedef _Float16 half8 __attribute__((ext_vector_type(8)));

// ---------- hist: src & dst partial histograms in one dispatch, ushort-packed ----------
__global__ __launch_bounds__(256) void hist_kernel(const int* __restrict__ src,
                                                   const int* __restrict__ dst,
                                                   unsigned* __restrict__ partialD,
                                                   unsigned* __restrict__ partialS,
                                                   int E, int NP) {
    __shared__ unsigned hpk[RANGE / 2];
    int per = (NP / RANGE) * NSLICE;
    int b = blockIdx.x;
    int halfsel = b / per;           // 0 = dst histogram, 1 = src histogram
    int q = b % per;
    int r = q / NSLICE;
    int s = q % NSLICE;
    const int* arr = halfsel ? src : dst;
    unsigned* out = halfsel ? partialS : partialD;
    int v0 = r * RANGE;
    int tid = threadIdx.x;
    for (int i = tid; i < RANGE / 2; i += 256) hpk[i] = 0;
    __syncthreads();
    int e0 = (int)((long long)E * s / NSLICE);
    int e1 = (int)((long long)E * (s + 1) / NSLICE);
    for (int e = e0 + tid; e < e1; e += 256) {
        unsigned d = (unsigned)(arr[e] - v0);
        if (d < RANGE) atomicAdd(&hpk[d >> 1], (d & 1) ? 65536u : 1u);
    }
    __syncthreads();
    size_t wbase = ((size_t)s * NP + v0) >> 1;
    for (int i = tid; i < RANGE / 2; i += 256) out[wbase + i] = hpk[i];
}

// ---------- scan phase 1: per-node slice-sums + deg_in + norms ----------
__global__ __launch_bounds__(256) void scanp1_kernel(const unsigned short* __restrict__ pD,
                                                     const unsigned short* __restrict__ pS,
                                                     int* __restrict__ blockSums,
                                                     float* __restrict__ ns,
                                                     float* __restrict__ nd,
                                                     int NP, int n) {
    __shared__ int buf[256];
    int tid = threadIdx.x;
    int v = blockIdx.x * 256 + tid;
    int ssum = 0, osum = 0;
    #pragma unroll
    for (int s = 0; s < NSLICE; ++s) {
        ssum += pD[(size_t)s * NP + v];
        osum += pS[(size_t)s * NP + v];
    }
    if (v < n) {
        ns[v] = 1.0f / sqrtf((float)(osum < 1 ? 1 : osum));
        nd[v] = 1.0f / sqrtf((float)(ssum < 1 ? 1 : ssum));
    }
    buf[tid] = ssum;
    __syncthreads();
    #pragma unroll
    for (int off = 1; off < 256; off <<= 1) {
        int t = (tid >= off) ? buf[tid - off] : 0;
        __syncthreads();
        buf[tid] += t;
        __syncthreads();
    }
    if (tid == 255) blockSums[blockIdx.x] = buf[255];
}

// ---------- scan phase 2 ----------
__global__ __launch_bounds__(256) void scanp2_kernel(const int* __restrict__ blockSums,
                                                     int* __restrict__ blockOffs, int nb) {
    __shared__ int buf[256];
    int tid = threadIdx.x;
    int v = (tid < nb) ? blockSums[tid] : 0;
    buf[tid] = v;
    __syncthreads();
    #pragma unroll
    for (int off = 1; off < 256; off <<= 1) {
        int t = (tid >= off) ? buf[tid - off] : 0;
        __syncthreads();
        buf[tid] += t;
        __syncthreads();
    }
    if (tid < nb) blockOffs[tid] = buf[tid] - v;
}

// ---------- scan phase 3: per-(node,slice) cursors + compact offsets ----------
__global__ __launch_bounds__(256) void scanp3_kernel(const unsigned short* __restrict__ pD,
                                                     const int* __restrict__ blockOffs,
                                                     int* __restrict__ cursorV,
                                                     int* __restrict__ offsc,
                                                     int NP, int n) {
    __shared__ int buf[256];
    int tid = threadIdx.x;
    int v = blockIdx.x * 256 + tid;
    int ssum = 0;
    #pragma unroll
    for (int s = 0; s < NSLICE; ++s) ssum += pD[(size_t)s * NP + v];
    buf[tid] = ssum;
    __syncthreads();
    #pragma unroll
    for (int off = 1; off < 256; off <<= 1) {
        int t = (tid >= off) ? buf[tid - off] : 0;
        __syncthreads();
        buf[tid] += t;
        __syncthreads();
    }
    int o = blockOffs[blockIdx.x] + buf[tid] - ssum;
    if (v <= n) offsc[v] = o;          // pad nodes have zero edges -> v==n gets total
    int* cv = cursorV + (size_t)v * NSLICE;
    #pragma unroll
    for (int s = 0; s < NSLICE; ++s) {
        int val = pD[(size_t)s * NP + v];
        cv[s] = o;
        o += val;
    }
}

// ---------- fill: place edges via LDS cursors (XCD-swizzled slices) ----------
__global__ __launch_bounds__(256) void fill_kernel(const int* __restrict__ src,
                                                   const int* __restrict__ dst,
                                                   const int* __restrict__ cursorV,
                                                   int* __restrict__ esrc, int E, int NP) {
    __shared__ int cur[RANGE];
    int b = blockIdx.x;
    int r = b / NSLICE;
    int inner = b % NSLICE;
    int s = ((inner & 7) << 3) | (inner >> 3);
    int v0 = r * RANGE;
    int tid = threadIdx.x;
    for (int i = tid; i < RANGE; i += 256)
        cur[i] = cursorV[(size_t)(v0 + i) * NSLICE + s];
    __syncthreads();
    int e0 = (int)((long long)E * s / NSLICE);
    int e1 = (int)((long long)E * (s + 1) / NSLICE);
    for (int e = e0 + tid; e < e1; e += 256) {
        unsigned dd = (unsigned)(dst[e] - v0);
        if (dd < RANGE) {
            int p = atomicAdd(&cur[dd], 1);
            esrc[p] = src[e];
        }
    }
}

// ---------- prescale: xh = fp16(in_feat * ns) ----------
__global__ void prescale_kernel(const float* __restrict__ x, const float* __restrict__ ns,
                                _Float16* __restrict__ xh, int n) {
    int i = blockIdx.x * blockDim.x + threadIdx.x;   // one thread per 8 elements
    if (i >= n * (FEAT / 8)) return;
    int v = i >> 4;
    float w = ns[v];
    float4 t0 = ((const float4*)x)[i * 2];
    float4 t1 = ((const float4*)x)[i * 2 + 1];
    half8 h;
    h[0] = (_Float16)(t0.x * w); h[1] = (_Float16)(t0.y * w);
    h[2] = (_Float16)(t0.z * w); h[3] = (_Float16)(t0.w * w);
    h[4] = (_Float16)(t1.x * w); h[5] = (_Float16)(t1.y * w);
    h[6] = (_Float16)(t1.z * w); h[7] = (_Float16)(t1.w * w);
    ((float4*)xh)[i] = __builtin_bit_cast(float4, h);
}

// ---------- aggregation: fp16 gather (256 B/row), fp32 accumulate ----------
__global__ __launch_bounds__(256) void agg_kernel(const _Float16* __restrict__ x,
                                                  const int* __restrict__ offs,
                                                  const int* __restrict__ esrc,
                                                  const float* __restrict__ nd,
                                                  float* __restrict__ m, int n) {
    int gid = blockIdx.x * blockDim.x + threadIdx.x;
    int v = gid >> 6;
    if (v >= n) return;
    int lane = threadIdx.x & 63;
    int q = lane >> 4;       // quarter 0..3: independent edge stream, stride 4
    int c = lane & 15;       // 16 lanes x 16B cover a 128-half row; lane c = cols 8c..8c+7
    int s0 = offs[v], s1 = offs[v + 1];
    float a0[8] = {0,0,0,0,0,0,0,0};
    float a1[8] = {0,0,0,0,0,0,0,0};
    float a2[8] = {0,0,0,0,0,0,0,0};
    float a3[8] = {0,0,0,0,0,0,0,0};
    int j = s0 + q;
    for (; j + 12 < s1; j += 16) {
        int e0 = esrc[j], e1 = esrc[j + 4], e2 = esrc[j + 8], e3 = esrc[j + 12];
        float4 r0 = ((const float4*)(x + (size_t)e0 * FEAT))[c];
        float4 r1 = ((const float4*)(x + (size_t)e1 * FEAT))[c];
        float4 r2 = ((const float4*)(x + (size_t)e2 * FEAT))[c];
        float4 r3 = ((const float4*)(x + (size_t)e3 * FEAT))[c];
        half8 h0 = __builtin_bit_cast(half8, r0);
        half8 h1 = __builtin_bit_cast(half8, r1);
        half8 h2 = __builtin_bit_cast(half8, r2);
        half8 h3 = __builtin_bit_cast(half8, r3);
        #pragma unroll
        for (int k = 0; k < 8; ++k) {
            a0[k] += (float)h0[k];
            a1[k] += (float)h1[k];
            a2[k] += (float)h2[k];
            a3[k] += (float)h3[k];
        }
    }
    for (; j < s1; j += 4) {
        int e0 = esrc[j];
        float4 r0 = ((const float4*)(x + (size_t)e0 * FEAT))[c];
        half8 h0 = __builtin_bit_cast(half8, r0);
        #pragma unroll
        for (int k = 0; k < 8; ++k) a0[k] += (float)h0[k];
    }
    float r[8];
    #pragma unroll
    for (int k = 0; k < 8; ++k) r[k] = (a0[k] + a1[k]) + (a2[k] + a3[k]);
    #pragma unroll
    for (int k = 0; k < 8; ++k) {
        r[k] += __shfl_xor(r[k], 16);
        r[k] += __shfl_xor(r[k], 32);
    }
    if (lane < 16) {
        float sc = nd[v];
        float4 o0, o1;
        o0.x = r[0] * sc; o0.y = r[1] * sc; o0.z = r[2] * sc; o0.w = r[3] * sc;
        o1.x = r[4] * sc; o1.y = r[5] * sc; o1.z = r[6] * sc; o1.w = r[7] * sc;
        ((float4*)(m + (size_t)v * FEAT))[c * 2] = o0;
        ((float4*)(m + (size_t)v * FEAT))[c * 2 + 1] = o1;
    }
}

// ---------- GEMM: 128x128 tile, 256 threads (4 waves), 8x8 blocking ----------
template<int MODE>   // 0: relu*ns -> fp16 (mid layer)   1: last layer (fp32 h + threshold)
__global__ __launch_bounds__(256) void gemm_kernel(const float* __restrict__ M,
                                                   const float* __restrict__ W,
                                                   const float* __restrict__ bias,
                                                   const float* __restrict__ nsv,
                                                   float* __restrict__ out,
                                                   float* __restrict__ out2, int n) {
    __shared__ float MsT[32][132];   // [k][row] transposed, stride 132 (16B-aligned, odd/32 banks)
    __shared__ float Ws[32][128];
    __shared__ float ns_s[128];
    int tid = threadIdx.x;
    int tx = tid & 15;     // cols tx*4..+3 and 64+tx*4..+3
    int ty = tid >> 4;     // rows ty*8..+7  (16 groups x 8 = 128 rows)
    int r0 = blockIdx.x * 128;
    if (MODE == 0 && tid < 128) ns_s[tid] = (r0 + tid < n) ? nsv[r0 + tid] : 1.0f;

    float acc[8][8];
    #pragma unroll
    for (int r = 0; r < 8; ++r)
        #pragma unroll
        for (int i = 0; i < 8; ++i) acc[r][i] = 0.f;

    for (int k0 = 0; k0 < FEAT; k0 += 32) {
        if (k0) __syncthreads();
        // stage W chunk: 1024 float4, 4 per thread
        #pragma unroll
        for (int i = 0; i < 4; ++i) {
            int idx = tid + i * 256;
            ((float4*)&Ws[0][0])[idx] = ((const float4*)(W + (size_t)k0 * FEAT))[idx];
        }
        // stage M tile transposed: 1024 float4, 4 per thread
        #pragma unroll
        for (int jj = 0; jj < 4; ++jj) {
            int i = tid + jj * 256;
            int row = i >> 3, c4 = i & 7;
            int gr = r0 + row;
            float4 v = make_float4(0.f, 0.f, 0.f, 0.f);
            if (gr < n) v = *(const float4*)(M + (size_t)gr * FEAT + k0 + c4 * 4);
            MsT[c4 * 4 + 0][row] = v.x;
            MsT[c4 * 4 + 1][row] = v.y;
            MsT[c4 * 4 + 2][row] = v.z;
            MsT[c4 * 4 + 3][row] = v.w;
        }
        __syncthreads();
        #pragma unroll 8
        for (int kk = 0; kk < 32; ++kk) {
            float4 a0 = *(const float4*)&MsT[kk][ty * 8];
            float4 a1 = *(const float4*)&MsT[kk][ty * 8 + 4];
            float4 w0 = *(const float4*)&Ws[kk][tx * 4];
            float4 w1 = *(const float4*)&Ws[kk][64 + tx * 4];
            float a[8] = {a0.x, a0.y, a0.z, a0.w, a1.x, a1.y, a1.z, a1.w};
            float w[8] = {w0.x, w0.y, w0.z, w0.w, w1.x, w1.y, w1.z, w1.w};
            #pragma unroll
            for (int r = 0; r < 8; ++r)
                #pragma unroll
                for (int i = 0; i < 8; ++i)
                    acc[r][i] = fmaf(a[r], w[i], acc[r][i]);
        }
    }

    float4 b0 = *(const float4*)&bias[tx * 4];
    float4 b1 = *(const float4*)&bias[64 + tx * 4];
    #pragma unroll
    for (int r = 0; r < 8; ++r) {
        int row = r0 + ty * 8 + r;
        if (row < n) {
            float4 v0, v1;
            v0.x = acc[r][0] + b0.x; v0.y = acc[r][1] + b0.y;
            v0.z = acc[r][2] + b0.z; v0.w = acc[r][3] + b0.w;
            v1.x = acc[r][4] + b1.x; v1.y = acc[r][5] + b1.y;
            v1.z = acc[r][6] + b1.z; v1.w = acc[r][7] + b1.w;
            v0.x = v0.x > 0.f ? v0.x : 0.f; v0.y = v0.y > 0.f ? v0.y : 0.f;
            v0.z = v0.z > 0.f ? v0.z : 0.f; v0.w = v0.w > 0.f ? v0.w : 0.f;
            v1.x = v1.x > 0.f ? v1.x : 0.f; v1.y = v1.y > 0.f ? v1.y : 0.f;
            v1.z = v1.z > 0.f ? v1.z : 0.f; v1.w = v1.w > 0.f ? v1.w : 0.f;
            if (MODE == 0) {
                float sc_ = ns_s[ty * 8 + r];
                union { _Float16 h[4]; float2 f; } u0, u1;
                u0.h[0] = (_Float16)(v0.x * sc_); u0.h[1] = (_Float16)(v0.y * sc_);
                u0.h[2] = (_Float16)(v0.z * sc_); u0.h[3] = (_Float16)(v0.w * sc_);
                u1.h[0] = (_Float16)(v1.x * sc_); u1.h[1] = (_Float16)(v1.y * sc_);
                u1.h[2] = (_Float16)(v1.z * sc_); u1.h[3] = (_Float16)(v1.w * sc_);
                _Float16* oh = (_Float16*)out;
                *(float2*)(oh + (size_t)row * FEAT + tx * 4) = u0.f;
                *(float2*)(oh + (size_t)row * FEAT + 64 + tx * 4) = u1.f;
            } else {
                *(float4*)(out + (size_t)row * FEAT + tx * 4) = v0;
                *(float4*)(out + (size_t)row * FEAT + 64 + tx * 4) = v1;
                float4 c0, c1;
                c0.x = v0.x >= 0.5f ? 1.f : 0.f; c0.y = v0.y >= 0.5f ? 1.f : 0.f;
                c0.z = v0.z >= 0.5f ? 1.f : 0.f; c0.w = v0.w >= 0.5f ? 1.f : 0.f;
                c1.x = v1.x >= 0.5f ? 1.f : 0.f; c1.y = v1.y >= 0.5f ? 1.f : 0.f;
                c1.z = v1.z >= 0.5f ? 1.f : 0.f; c1.w = v1.w >= 0.5f ? 1.f : 0.f;
                *(float4*)(out2 + (size_t)row * FEAT + tx * 4) = c0;
                *(float4*)(out2 + (size_t)row * FEAT + 64 + tx * 4) = c1;
            }
        }
    }
}

extern "C" void kernel_launch(void* const* d_in, const int* in_sizes, int n_in,
                              void* d_out, int out_size, void* d_ws, size_t ws_size,
                              hipStream_t stream) {
    const float* in_feat = (const float*)d_in[0];
    const int*   src     = (const int*)d_in[1];
    const int*   dst     = (const int*)d_in[2];
    const float* W[5] = {(const float*)d_in[3], (const float*)d_in[5], (const float*)d_in[7],
                         (const float*)d_in[9], (const float*)d_in[11]};
    const float* B[5] = {(const float*)d_in[4], (const float*)d_in[6], (const float*)d_in[8],
                         (const float*)d_in[10], (const float*)d_in[12]};
    const int E = in_sizes[1];
    const int N = in_sizes[0] / FEAT;
    const int NRANGE = (N + RANGE - 1) / RANGE;       // 4
    const int NP = NRANGE * RANGE;                    // 51200
    const size_t MTOT = (size_t)NP * NSLICE;          // 3,276,800

    char* ws = (char*)d_ws;
    size_t off = 0;
    auto alloc = [&](size_t bytes) { size_t o = off; off += (bytes + 255) & ~size_t(255); return o; };
    unsigned* partialD = (unsigned*)(ws + alloc(MTOT * 2));
    size_t    pS_off   = alloc(MTOT * 2);
    unsigned* partialS = (unsigned*)(ws + pS_off);
    int*      esrc     = (int*)(ws + pS_off);          // aliases partialS (dead after scanp1)
    size_t    cV_off   = alloc(MTOT * 4);
    int*      cursorV  = (int*)(ws + cV_off);
    _Float16* xh       = (_Float16*)(ws + cV_off);     // aliases cursorV (dead after fill); 12.8MB <= 13.1MB
    float*    ns       = (float*)(ws + alloc((size_t)N * 4));
    float*    nd       = (float*)(ws + alloc((size_t)N * 4));
    int*      offsc    = (int*)(ws + alloc((size_t)(N + 1) * 4));
    int*      blockSums = (int*)(ws + alloc(1024));
    int*      blockOffs = (int*)(ws + alloc(1024));

    float* out_h = (float*)d_out;                     // m scratch; h5 at the end
    float* out_c = out_h + (size_t)N * FEAT;          // threshold output at the end

    const int histBlocks = 2 * NRANGE * NSLICE;       // 512
    const int scanBlocks = NP / 256;                  // 200
    hist_kernel<<<histBlocks, 256, 0, stream>>>(src, dst, partialD, partialS, E, NP);
    scanp1_kernel<<<scanBlocks, 256, 0, stream>>>((const unsigned short*)partialD,
                                                  (const unsigned short*)partialS,
                                                  blockSums, ns, nd, NP, N);
    scanp2_kernel<<<1, 256, 0, stream>>>(blockSums, blockOffs, scanBlocks);
    scanp3_kernel<<<scanBlocks, 256, 0, stream>>>((const unsigned short*)partialD,
                                                  blockOffs, cursorV, offsc, NP, N);
    fill_kernel<<<NRANGE * NSLICE, 256, 0, stream>>>(src, dst, cursorV, esrc, E, NP);
    // prescale AFTER fill: xh aliases cursorV
    prescale_kernel<<<(N * (FEAT / 8) + 255) / 256, 256, 0, stream>>>(in_feat, ns, xh, N);

    const int agg_blocks = (int)(((size_t)N * 64 + 255) / 256);
    const int gemm_blocks = (N + 127) / 128;

    for (int l = 0; l < 5; ++l) {
        agg_kernel<<<agg_blocks, 256, 0, stream>>>(xh, offsc, esrc, nd, out_h, N);
        if (l < 4)
            gemm_kernel<0><<<gemm_blocks, 256, 0, stream>>>(out_h, W[l], B[l], ns, (float*)xh, nullptr, N);
        else
            gemm_kernel<1><<<gemm_blocks, 256, 0, stream>>>(out_h, W[l], B[l], ns, out_h, out_c, N);
    }
}

// Round 3
// 465.519 us; speedup vs baseline: 1.2897x; 1.1315x over previous
//
#include <hip/hip_runtime.h>

#define FEAT 128
#define RANGE 12800
#define NSLICE 64

typedef _Float16 half8 __attribute__((ext_vector_type(8)));
typedef _Float16 half4v __attribute__((ext_vector_type(4)));
typedef float f32x4 __attribute__((ext_vector_type(4)));

// ---------- hist: src & dst partial histograms in one dispatch, ushort-packed ----------
__global__ __launch_bounds__(1024) void hist_kernel(const int* __restrict__ src,
                                                    const int* __restrict__ dst,
                                                    unsigned* __restrict__ partialD,
                                                    unsigned* __restrict__ partialS,
                                                    int E, int NP) {
    __shared__ unsigned hpk[RANGE / 2];
    int per = (NP / RANGE) * NSLICE;
    int b = blockIdx.x;
    int halfsel = b / per;           // 0 = dst histogram, 1 = src histogram
    int q = b % per;
    int r = q / NSLICE;
    int s = q % NSLICE;
    const int* arr = halfsel ? src : dst;
    unsigned* out = halfsel ? partialS : partialD;
    int v0 = r * RANGE;
    int tid = threadIdx.x;
    for (int i = tid; i < RANGE / 2; i += 1024) hpk[i] = 0;
    __syncthreads();
    int e0 = (int)((long long)E * s / NSLICE);
    int e1 = (int)((long long)E * (s + 1) / NSLICE);
    for (int e = e0 + tid; e < e1; e += 1024) {
        unsigned d = (unsigned)(arr[e] - v0);
        if (d < RANGE) atomicAdd(&hpk[d >> 1], (d & 1) ? 65536u : 1u);
    }
    __syncthreads();
    size_t wbase = ((size_t)s * NP + v0) >> 1;
    for (int i = tid; i < RANGE / 2; i += 1024) out[wbase + i] = hpk[i];
}

// ---------- scan phase 1: per-node slice-sums + deg_in + norms ----------
__global__ __launch_bounds__(256) void scanp1_kernel(const unsigned short* __restrict__ pD,
                                                     const unsigned short* __restrict__ pS,
                                                     int* __restrict__ blockSums,
                                                     float* __restrict__ ns,
                                                     float* __restrict__ nd,
                                                     int NP, int n) {
    __shared__ int buf[256];
    int tid = threadIdx.x;
    int v = blockIdx.x * 256 + tid;
    int ssum = 0, osum = 0;
    #pragma unroll
    for (int s = 0; s < NSLICE; ++s) {
        ssum += pD[(size_t)s * NP + v];
        osum += pS[(size_t)s * NP + v];
    }
    if (v < n) {
        ns[v] = 1.0f / sqrtf((float)(osum < 1 ? 1 : osum));
        nd[v] = 1.0f / sqrtf((float)(ssum < 1 ? 1 : ssum));
    }
    buf[tid] = ssum;
    __syncthreads();
    #pragma unroll
    for (int off = 1; off < 256; off <<= 1) {
        int t = (tid >= off) ? buf[tid - off] : 0;
        __syncthreads();
        buf[tid] += t;
        __syncthreads();
    }
    if (tid == 255) blockSums[blockIdx.x] = buf[255];
}

// ---------- scan phase 2 ----------
__global__ __launch_bounds__(256) void scanp2_kernel(const int* __restrict__ blockSums,
                                                     int* __restrict__ blockOffs, int nb) {
    __shared__ int buf[256];
    int tid = threadIdx.x;
    int v = (tid < nb) ? blockSums[tid] : 0;
    buf[tid] = v;
    __syncthreads();
    #pragma unroll
    for (int off = 1; off < 256; off <<= 1) {
        int t = (tid >= off) ? buf[tid - off] : 0;
        __syncthreads();
        buf[tid] += t;
        __syncthreads();
    }
    if (tid < nb) blockOffs[tid] = buf[tid] - v;
}

// ---------- scan phase 3: per-(node,slice) cursors + compact offsets ----------
__global__ __launch_bounds__(256) void scanp3_kernel(const unsigned short* __restrict__ pD,
                                                     const int* __restrict__ blockOffs,
                                                     int* __restrict__ cursorV,
                                                     int* __restrict__ offsc,
                                                     int NP, int n) {
    __shared__ int buf[256];
    int tid = threadIdx.x;
    int v = blockIdx.x * 256 + tid;
    int ssum = 0;
    #pragma unroll
    for (int s = 0; s < NSLICE; ++s) ssum += pD[(size_t)s * NP + v];
    buf[tid] = ssum;
    __syncthreads();
    #pragma unroll
    for (int off = 1; off < 256; off <<= 1) {
        int t = (tid >= off) ? buf[tid - off] : 0;
        __syncthreads();
        buf[tid] += t;
        __syncthreads();
    }
    int o = blockOffs[blockIdx.x] + buf[tid] - ssum;
    if (v <= n) offsc[v] = o;          // pad nodes have zero edges -> v==n gets total
    int* cv = cursorV + (size_t)v * NSLICE;
    #pragma unroll
    for (int s = 0; s < NSLICE; ++s) {
        int val = pD[(size_t)s * NP + v];
        cv[s] = o;
        o += val;
    }
}

// ---------- fill: place edges via LDS cursors (XCD-swizzled slices) ----------
__global__ __launch_bounds__(1024) void fill_kernel(const int* __restrict__ src,
                                                    const int* __restrict__ dst,
                                                    const int* __restrict__ cursorV,
                                                    int* __restrict__ esrc, int E, int NP) {
    __shared__ int cur[RANGE];
    int b = blockIdx.x;
    int r = b / NSLICE;
    int inner = b % NSLICE;
    int s = ((inner & 7) << 3) | (inner >> 3);
    int v0 = r * RANGE;
    int tid = threadIdx.x;
    for (int i = tid; i < RANGE; i += 1024)
        cur[i] = cursorV[(size_t)(v0 + i) * NSLICE + s];
    __syncthreads();
    int e0 = (int)((long long)E * s / NSLICE);
    int e1 = (int)((long long)E * (s + 1) / NSLICE);
    for (int e = e0 + tid; e < e1; e += 1024) {
        unsigned dd = (unsigned)(dst[e] - v0);
        if (dd < RANGE) {
            int p = atomicAdd(&cur[dd], 1);
            esrc[p] = src[e];
        }
    }
}

// ---------- prescale: xh = fp16(in_feat * ns) ----------
__global__ void prescale_kernel(const float* __restrict__ x, const float* __restrict__ ns,
                                _Float16* __restrict__ xh, int n) {
    int i = blockIdx.x * blockDim.x + threadIdx.x;   // one thread per 8 elements
    if (i >= n * (FEAT / 8)) return;
    int v = i >> 4;
    float w = ns[v];
    float4 t0 = ((const float4*)x)[i * 2];
    float4 t1 = ((const float4*)x)[i * 2 + 1];
    half8 h;
    h[0] = (_Float16)(t0.x * w); h[1] = (_Float16)(t0.y * w);
    h[2] = (_Float16)(t0.z * w); h[3] = (_Float16)(t0.w * w);
    h[4] = (_Float16)(t1.x * w); h[5] = (_Float16)(t1.y * w);
    h[6] = (_Float16)(t1.z * w); h[7] = (_Float16)(t1.w * w);
    ((float4*)xh)[i] = __builtin_bit_cast(float4, h);
}

// ---------- W prep: fp16 value+residual, transposed to [col][k] ----------
__global__ __launch_bounds__(256) void wprep_kernel(const float* __restrict__ Wa,
                                                    const float* __restrict__ Wb,
                                                    const float* __restrict__ Wc,
                                                    const float* __restrict__ Wd,
                                                    const float* __restrict__ We,
                                                    _Float16* __restrict__ w16t,
                                                    _Float16* __restrict__ wrt) {
    int gid = blockIdx.x * 256 + threadIdx.x;        // 5 * 128 * 128 = 81920
    int l = gid >> 14;
    int idx = gid & 16383;
    int col = idx >> 7;
    int k = idx & 127;
    const float* Wp = (l == 0) ? Wa : (l == 1) ? Wb : (l == 2) ? Wc : (l == 3) ? Wd : We;
    float w = Wp[k * FEAT + col];
    _Float16 h = (_Float16)w;
    _Float16 r = (_Float16)(w - (float)h);
    w16t[gid] = h;
    wrt[gid] = r;
}

// ---------- aggregation: fp16 gather (256 B/row), fp32 accumulate ----------
__global__ __launch_bounds__(256) void agg_kernel(const _Float16* __restrict__ x,
                                                  const int* __restrict__ offs,
                                                  const int* __restrict__ esrc,
                                                  const float* __restrict__ nd,
                                                  float* __restrict__ m, int n) {
    int gid = blockIdx.x * blockDim.x + threadIdx.x;
    int v = gid >> 6;
    if (v >= n) return;
    int lane = threadIdx.x & 63;
    int q = lane >> 4;       // quarter 0..3: independent edge stream, stride 4
    int c = lane & 15;       // 16 lanes x 16B cover a 128-half row; lane c = cols 8c..8c+7
    int s0 = offs[v], s1 = offs[v + 1];
    float a0[8] = {0,0,0,0,0,0,0,0};
    float a1[8] = {0,0,0,0,0,0,0,0};
    float a2[8] = {0,0,0,0,0,0,0,0};
    float a3[8] = {0,0,0,0,0,0,0,0};
    int j = s0 + q;
    for (; j + 12 < s1; j += 16) {
        int e0 = esrc[j], e1 = esrc[j + 4], e2 = esrc[j + 8], e3 = esrc[j + 12];
        float4 r0 = ((const float4*)(x + (size_t)e0 * FEAT))[c];
        float4 r1 = ((const float4*)(x + (size_t)e1 * FEAT))[c];
        float4 r2 = ((const float4*)(x + (size_t)e2 * FEAT))[c];
        float4 r3 = ((const float4*)(x + (size_t)e3 * FEAT))[c];
        half8 h0 = __builtin_bit_cast(half8, r0);
        half8 h1 = __builtin_bit_cast(half8, r1);
        half8 h2 = __builtin_bit_cast(half8, r2);
        half8 h3 = __builtin_bit_cast(half8, r3);
        #pragma unroll
        for (int k = 0; k < 8; ++k) {
            a0[k] += (float)h0[k];
            a1[k] += (float)h1[k];
            a2[k] += (float)h2[k];
            a3[k] += (float)h3[k];
        }
    }
    for (; j < s1; j += 4) {
        int e0 = esrc[j];
        float4 r0 = ((const float4*)(x + (size_t)e0 * FEAT))[c];
        half8 h0 = __builtin_bit_cast(half8, r0);
        #pragma unroll
        for (int k = 0; k < 8; ++k) a0[k] += (float)h0[k];
    }
    float r[8];
    #pragma unroll
    for (int k = 0; k < 8; ++k) r[k] = (a0[k] + a1[k]) + (a2[k] + a3[k]);
    #pragma unroll
    for (int k = 0; k < 8; ++k) {
        r[k] += __shfl_xor(r[k], 16);
        r[k] += __shfl_xor(r[k], 32);
    }
    if (lane < 16) {
        float sc = nd[v];
        float4 o0, o1;
        o0.x = r[0] * sc; o0.y = r[1] * sc; o0.z = r[2] * sc; o0.w = r[3] * sc;
        o1.x = r[4] * sc; o1.y = r[5] * sc; o1.z = r[6] * sc; o1.w = r[7] * sc;
        ((float4*)(m + (size_t)v * FEAT))[c * 2] = o0;
        ((float4*)(m + (size_t)v * FEAT))[c * 2 + 1] = o1;
    }
}

// ---------- GEMM: MFMA f16 with value+residual (numerically ~fp32 exact) ----------
// A (fp32 in) split in registers -> A16+Ar in LDS; W pre-split transposed [col][k].
// acc = A16*W16 + A16*Wr + Ar*W16  (drops Ar*Wr ~ 2.4e-7 rel)
// 32x128 tile, 256 threads (4 waves: 2 row x 2 col), 80KB LDS -> 2 blocks/CU.
template<int MODE>   // 0: relu*ns -> fp16   1: last layer (fp32 h + threshold)
__global__ __launch_bounds__(256) void gemm_kernel(const float* __restrict__ M,
                                                   const _Float16* __restrict__ w16t,
                                                   const _Float16* __restrict__ wrt,
                                                   const float* __restrict__ bias,
                                                   const float* __restrict__ nsv,
                                                   _Float16* __restrict__ outh,
                                                   float* __restrict__ outf,
                                                   float* __restrict__ out2, int n) {
    __shared__ _Float16 A16s[32 * 128];
    __shared__ _Float16 Ars[32 * 128];
    __shared__ _Float16 W16s[128 * 128];
    __shared__ _Float16 Wrs[128 * 128];
    int tid = threadIdx.x;
    int r0 = blockIdx.x * 32;

    // stage W (value+residual), XOR-swizzled 16B chunks: chunk ^= (col&7)
    #pragma unroll
    for (int j = 0; j < 8; ++j) {
        int i = tid + j * 256;             // 2048 float4 per array
        int col = i >> 4, ch = i & 15;
        int d = col * 16 + (ch ^ (col & 7));
        ((float4*)W16s)[d] = ((const float4*)w16t)[i];
        ((float4*)Wrs)[d]  = ((const float4*)wrt)[i];
    }
    // stage A rows r0..r0+31: fp32 -> fp16 value + residual, swizzled
    #pragma unroll
    for (int j = 0; j < 4; ++j) {
        int i = tid + j * 256;             // 1024 float4 of source fp32
        int row = i >> 5, c4 = i & 31;
        int gr = r0 + row;
        float4 v = make_float4(0.f, 0.f, 0.f, 0.f);
        if (gr < n) v = ((const float4*)(M + (size_t)gr * FEAT))[c4];
        half4v h, rr;
        h[0] = (_Float16)v.x; h[1] = (_Float16)v.y; h[2] = (_Float16)v.z; h[3] = (_Float16)v.w;
        rr[0] = (_Float16)(v.x - (float)h[0]); rr[1] = (_Float16)(v.y - (float)h[1]);
        rr[2] = (_Float16)(v.z - (float)h[2]); rr[3] = (_Float16)(v.w - (float)h[3]);
        int d = row * 128 + (((c4 >> 1) ^ (row & 7)) << 3) + ((c4 & 1) << 2);
        *(half4v*)(A16s + d) = h;
        *(half4v*)(Ars + d) = rr;
    }
    __syncthreads();

    int lane = tid & 63;
    int w = tid >> 6;
    int l15 = lane & 15;
    int q = lane >> 4;
    int rbase = (w & 1) * 16 + l15;        // A-frag row
    int cbase = (w >> 1) * 64;             // wave's 64-col strip

    f32x4 acc[4] = {{0.f,0.f,0.f,0.f},{0.f,0.f,0.f,0.f},{0.f,0.f,0.f,0.f},{0.f,0.f,0.f,0.f}};
    #pragma unroll
    for (int ks = 0; ks < 4; ++ks) {
        int chunk = ks * 4 + q;
        int aoff = rbase * 128 + ((chunk ^ (rbase & 7)) << 3);
        half8 a16 = *(const half8*)(A16s + aoff);
        half8 ar  = *(const half8*)(Ars + aoff);
        #pragma unroll
        for (int ct = 0; ct < 4; ++ct) {
            int col = cbase + ct * 16 + l15;
            int boff = col * 128 + ((chunk ^ (col & 7)) << 3);
            half8 b16 = *(const half8*)(W16s + boff);
            half8 br  = *(const half8*)(Wrs + boff);
            acc[ct] = __builtin_amdgcn_mfma_f32_16x16x32_f16(a16, b16, acc[ct], 0, 0, 0);
            acc[ct] = __builtin_amdgcn_mfma_f32_16x16x32_f16(a16, br,  acc[ct], 0, 0, 0);
            acc[ct] = __builtin_amdgcn_mfma_f32_16x16x32_f16(ar,  b16, acc[ct], 0, 0, 0);
        }
    }

    // epilogue: C/D layout col=lane&15, row=(lane>>4)*4+reg
    int rloc = (w & 1) * 16 + q * 4;
    float scv[4];
    #pragma unroll
    for (int reg = 0; reg < 4; ++reg) {
        int row = r0 + rloc + reg;
        scv[reg] = (MODE == 0 && row < n) ? nsv[row] : 1.0f;
    }
    #pragma unroll
    for (int ct = 0; ct < 4; ++ct) {
        int col = cbase + ct * 16 + l15;
        float b = bias[col];
        #pragma unroll
        for (int reg = 0; reg < 4; ++reg) {
            int row = r0 + rloc + reg;
            if (row < n) {
                float h = acc[ct][reg] + b;
                h = h > 0.f ? h : 0.f;
                if (MODE == 0) {
                    outh[(size_t)row * FEAT + col] = (_Float16)(h * scv[reg]);
                } else {
                    outf[(size_t)row * FEAT + col] = h;
                    out2[(size_t)row * FEAT + col] = h >= 0.5f ? 1.f : 0.f;
                }
            }
        }
    }
}

extern "C" void kernel_launch(void* const* d_in, const int* in_sizes, int n_in,
                              void* d_out, int out_size, void* d_ws, size_t ws_size,
                              hipStream_t stream) {
    const float* in_feat = (const float*)d_in[0];
    const int*   src     = (const int*)d_in[1];
    const int*   dst     = (const int*)d_in[2];
    const float* W[5] = {(const float*)d_in[3], (const float*)d_in[5], (const float*)d_in[7],
                         (const float*)d_in[9], (const float*)d_in[11]};
    const float* B[5] = {(const float*)d_in[4], (const float*)d_in[6], (const float*)d_in[8],
                         (const float*)d_in[10], (const float*)d_in[12]};
    const int E = in_sizes[1];
    const int N = in_sizes[0] / FEAT;
    const int NRANGE = (N + RANGE - 1) / RANGE;       // 4
    const int NP = NRANGE * RANGE;                    // 51200
    const size_t MTOT = (size_t)NP * NSLICE;          // 3,276,800

    char* ws = (char*)d_ws;
    size_t off = 0;
    auto alloc = [&](size_t bytes) { size_t o = off; off += (bytes + 255) & ~size_t(255); return o; };
    unsigned* partialD = (unsigned*)(ws + alloc(MTOT * 2));
    size_t    pS_off   = alloc(MTOT * 2);
    unsigned* partialS = (unsigned*)(ws + pS_off);
    int*      esrc     = (int*)(ws + pS_off);          // aliases partialS (dead after scanp1)
    size_t    cV_off   = alloc(MTOT * 4);
    int*      cursorV  = (int*)(ws + cV_off);
    _Float16* xh       = (_Float16*)(ws + cV_off);     // aliases cursorV (dead after fill); 12.8MB <= 13.1MB
    float*    ns       = (float*)(ws + alloc((size_t)N * 4));
    float*    nd       = (float*)(ws + alloc((size_t)N * 4));
    int*      offsc    = (int*)(ws + alloc((size_t)(N + 1) * 4));
    int*      blockSums = (int*)(ws + alloc(1024));
    int*      blockOffs = (int*)(ws + alloc(1024));
    _Float16* w16t     = (_Float16*)(ws + alloc(5 * 16384 * 2));
    _Float16* wrt      = (_Float16*)(ws + alloc(5 * 16384 * 2));

    float* out_h = (float*)d_out;                     // m scratch; h5 at the end
    float* out_c = out_h + (size_t)N * FEAT;          // threshold output at the end

    const int histBlocks = 2 * NRANGE * NSLICE;       // 512
    const int scanBlocks = NP / 256;                  // 200
    hist_kernel<<<histBlocks, 1024, 0, stream>>>(src, dst, partialD, partialS, E, NP);
    scanp1_kernel<<<scanBlocks, 256, 0, stream>>>((const unsigned short*)partialD,
                                                  (const unsigned short*)partialS,
                                                  blockSums, ns, nd, NP, N);
    scanp2_kernel<<<1, 256, 0, stream>>>(blockSums, blockOffs, scanBlocks);
    scanp3_kernel<<<scanBlocks, 256, 0, stream>>>((const unsigned short*)partialD,
                                                  blockOffs, cursorV, offsc, NP, N);
    fill_kernel<<<NRANGE * NSLICE, 1024, 0, stream>>>(src, dst, cursorV, esrc, E, NP);
    wprep_kernel<<<320, 256, 0, stream>>>(W[0], W[1], W[2], W[3], W[4], w16t, wrt);
    // prescale AFTER fill: xh aliases cursorV
    prescale_kernel<<<(N * (FEAT / 8) + 255) / 256, 256, 0, stream>>>(in_feat, ns, xh, N);

    const int agg_blocks = (int)(((size_t)N * 64 + 255) / 256);
    const int gemm_blocks = (N + 31) / 32;

    for (int l = 0; l < 5; ++l) {
        agg_kernel<<<agg_blocks, 256, 0, stream>>>(xh, offsc, esrc, nd, out_h, N);
        if (l < 4)
            gemm_kernel<0><<<gemm_blocks, 256, 0, stream>>>(out_h, w16t + (size_t)l * 16384,
                                                            wrt + (size_t)l * 16384, B[l], ns,
                                                            xh, nullptr, nullptr, N);
        else
            gemm_kernel<1><<<gemm_blocks, 256, 0, stream>>>(out_h, w16t + (size_t)l * 16384,
                                                            wrt + (size_t)l * 16384, B[l], nullptr,
                                                            nullptr, out_h, out_c, N);
    }
}